// Round 18
// baseline (160.607 us; speedup 1.0000x reference)
//
#include <hip/hip_runtime.h>

// Problem constants (B=4, T=2048, C=1024, H=16, dk=64, ffn=4096, nq=16)
#define M_TOK 8192
#define C_DIM 1024
#define F_DIM 4096
#define NQ    16

typedef __attribute__((ext_vector_type(8))) short short8v;
typedef __attribute__((ext_vector_type(4))) float f32x4;
typedef unsigned long long u64;

typedef __attribute__((address_space(1))) void as1_void;
typedef __attribute__((address_space(3))) void as3_void;

__device__ __forceinline__ void gld_lds16(const void* g, void* l) {
  __builtin_amdgcn_global_load_lds((as1_void*)g, (as3_void*)l, 16, 0, 0);
}

__device__ __forceinline__ unsigned short f2bf(float f) {
  unsigned int u = __float_as_uint(f);
  u += 0x7FFFu + ((u >> 16) & 1u);   // round-to-nearest-even
  return (unsigned short)(u >> 16);
}

// Verified mapping (rounds 2/6/7/11/14): D row (A-dim) = (lane>>4)*4 + reg, D col (B-dim) = lane&15.
__device__ __forceinline__ void mfma_16x16x32_bf16(f32x4& d, short8v a, short8v b) {
  asm("v_mfma_f32_16x16x32_bf16 %0, %1, %2, %0" : "+v"(d) : "v"(a), "v"(b));
}

// ---------------------------------------------------------------------------
// K1: per-head cumprod(cos) + residual + LN1.  (unchanged, verified)
// ---------------------------------------------------------------------------
__global__ __launch_bounds__(256) void k_attn_ln1(
    const float* __restrict__ x, const float* __restrict__ g1,
    const float* __restrict__ be1, float* __restrict__ x1,
    float* __restrict__ qf) {
  const int row  = blockIdx.x;
  const int tid  = threadIdx.x;
  const int lane = tid & 63;
  const int w    = tid >> 6;
  const float* xr = x + (size_t)row * C_DIM;

  float y[4];
  float s1 = 0.f, s2 = 0.f;
#pragma unroll
  for (int hi = 0; hi < 4; ++hi) {
    const int idx = (w * 4 + hi) * 64 + lane;
    const float v = xr[idx];
    float p = cosf(v);
#pragma unroll
    for (int off = 1; off < 64; off <<= 1) {
      const float up = __shfl_up(p, off, 64);
      if (lane >= off) p *= up;
    }
    const float yy = v + p;
    y[hi] = yy;
    s1 += yy;
    s2 += yy * yy;
  }
#pragma unroll
  for (int off = 32; off; off >>= 1) {
    s1 += __shfl_xor(s1, off, 64);
    s2 += __shfl_xor(s2, off, 64);
  }
  __shared__ float red[8];
  if (lane == 0) { red[w] = s1; red[4 + w] = s2; }
  __syncthreads();
  s1 = red[0] + red[1] + red[2] + red[3];
  s2 = red[4] + red[5] + red[6] + red[7];
  const float mu  = s1 * (1.f / C_DIM);
  const float var = s2 * (1.f / C_DIM) - mu * mu;   // biased, as torch
  const float rs  = rsqrtf(var + 1e-5f);

  float* x1r = x1 + (size_t)row * C_DIM;
#pragma unroll
  for (int hi = 0; hi < 4; ++hi) {
    const int idx = (w * 4 + hi) * 64 + lane;
    const float xv = (y[hi] - mu) * rs * g1[idx] + be1[idx];
    x1r[idx] = xv;
    if (w == 0 && hi == 0) {   // channels 0..63 live in wave 0 here
      const float c = cosf(xv);
      float run = 1.f, mine = 0.f;
#pragma unroll
      for (int k = 0; k < NQ; ++k) {
        const float ck = __shfl(c, k, 64);
        run *= ck;
        if (lane == k) mine = run;
      }
      if (lane < NQ) qf[(size_t)row * NQ + lane] = mine;
    }
  }
}

// ---------------------------------------------------------------------------
// K2: w2 fp32 -> bf16 (unchanged)
// ---------------------------------------------------------------------------
__global__ __launch_bounds__(256) void k_w2cast(const float* __restrict__ w2,
                                                unsigned short* __restrict__ w2b) {
  const int n4 = C_DIM * F_DIM / 4;
  for (int i = blockIdx.x * 256 + threadIdx.x; i < n4; i += gridDim.x * 256) {
    const float4 v = ((const float4*)w2)[i];
    u64 pk = (u64)f2bf(v.x) | ((u64)f2bf(v.y) << 16)
           | ((u64)f2bf(v.z) << 32) | ((u64)f2bf(v.w) << 48);
    ((u64*)w2b)[i] = pk;
  }
}

// ---------------------------------------------------------------------------
// K3 (v3): R = bf16(relu(q @ w1^T + b1)) — zero LDS / zero cross-thread.
// (unchanged from rounds 6-14 PASS)
// ---------------------------------------------------------------------------
__global__ __launch_bounds__(256) void k_ffn1(
    const float* __restrict__ qf, const float* __restrict__ w1,
    const float* __restrict__ b1, unsigned short* __restrict__ R) {
  const int tid  = threadIdx.x;
  const int lane = tid & 63;
  const int wv   = tid >> 6;
  const int r16  = lane & 15;
  const int hk   = lane >> 4;
  const int mb   = blockIdx.x * 16;              // 16 q-rows per block
  const int fb   = blockIdx.y * 64 + wv * 16;    // 16 f-cols per wave

  short8v a = short8v{0,0,0,0,0,0,0,0};
  short8v b = short8v{0,0,0,0,0,0,0,0};
  if (hk < 2) {   // k = hk*8 .. hk*8+7 < 16 carries real data; k>=16 stays 0
    const float* qa = qf + (size_t)(mb + r16) * NQ + hk * 8;
    const float4 a0 = *(const float4*)(qa);
    const float4 a1 = *(const float4*)(qa + 4);
    a[0] = (short)f2bf(a0.x); a[1] = (short)f2bf(a0.y);
    a[2] = (short)f2bf(a0.z); a[3] = (short)f2bf(a0.w);
    a[4] = (short)f2bf(a1.x); a[5] = (short)f2bf(a1.y);
    a[6] = (short)f2bf(a1.z); a[7] = (short)f2bf(a1.w);
    const float* wb = w1 + (size_t)(fb + r16) * NQ + hk * 8;
    const float4 b0 = *(const float4*)(wb);
    const float4 b1v = *(const float4*)(wb + 4);
    b[0] = (short)f2bf(b0.x); b[1] = (short)f2bf(b0.y);
    b[2] = (short)f2bf(b0.z); b[3] = (short)f2bf(b0.w);
    b[4] = (short)f2bf(b1v.x); b[5] = (short)f2bf(b1v.y);
    b[6] = (short)f2bf(b1v.z); b[7] = (short)f2bf(b1v.w);
  }

  f32x4 acc = {0.f, 0.f, 0.f, 0.f};
  mfma_16x16x32_bf16(acc, a, b);

  const int f = fb + r16;
  const float bn = b1[f];
#pragma unroll
  for (int r = 0; r < 4; ++r) {
    const int m = mb + hk * 4 + r;
    R[(size_t)m * F_DIM + f] = f2bf(fmaxf(acc[r] + bn, 0.f));
  }
}

// ---------------------------------------------------------------------------
// K4: R14-verified kernel (139.98us PASS) + SINGLE ADDITION: T1 XCD-aware
// bijective block swizzle (nwg%8==0 guard). XCD k gets n-tile k exclusively
// -> its 1MB W2 panel becomes L2-resident (default round-robin scatters
// n-tiles across XCDs; 8MB w2b never fits a 4MB L2).
// Wave grid 2Mx2Nx2K, triple-buffer 144KB, counted vmcnt(6), T2 swizzle.
// ---------------------------------------------------------------------------
#define BM 256
#define BN 128
#define BK 64
#define NT (F_DIM / BK)            // 64 K-tiles
#define ATILE (BM * BK)            // 16384 bf16 = 32KB
#define BTILE (BN * BK)            // 8192  bf16 = 16KB
#define TILE3 (ATILE + BTILE)      // 24576 bf16 = 48KB

__global__ __launch_bounds__(512) void k_gemm(
    const unsigned short* __restrict__ R, const unsigned short* __restrict__ W2,
    const float* __restrict__ b2, float* __restrict__ xio, int m_off) {
  __shared__ unsigned short L[3 * TILE3];   // 144KB
  const int tid = threadIdx.x;

  // T1: bijective XCD swizzle (dispatch order: x fastest -> lin % 8 = XCD).
  int bx = blockIdx.x, by = blockIdx.y;
  {
    const int nwg = gridDim.x * gridDim.y;
    if ((nwg & 7) == 0) {
      const int lin = by * gridDim.x + bx;
      const int cpx = nwg >> 3;
      const int nl  = (lin & 7) * cpx + (lin >> 3);
      bx = nl % gridDim.x;
      by = nl / gridDim.x;
    }
  }
  const int m0 = bx * BM;                   // chunk-local
  const int n0 = by * BN;
  const unsigned short* Ag = R + (size_t)m0 * F_DIM;
  const unsigned short* Bg = W2 + (size_t)n0 * F_DIM;

  const int lane = tid & 63;
  const int wv  = tid >> 6;     // 0..7
  const int kz  = wv >> 2;      // k-slice owner: 0 -> k 0..31, 1 -> k 32..63
  const int wq  = wv & 3;       // output-tile id (2M x 2N)
  const int wr  = wq >> 1;      // 0..1 (M dim, 128 rows each)
  const int wc  = wq & 1;       // 0..1 (N dim, 64 cols each)
  const int r16 = lane & 15;
  const int hk  = lane >> 4;
  const int ks  = hk + kz * 4;     // 8-elem k-group index within BK=64
  const int ar0 = wr * 128 + r16;  // A rows base for this lane
  const int br0 = wc * 64 + r16;   // B rows base

  f32x4 acc[8][4];
  const f32x4 fzero = {0.f, 0.f, 0.f, 0.f};
#pragma unroll
  for (int i = 0; i < 8; ++i)
#pragma unroll
    for (int j = 0; j < 4; ++j) acc[i][j] = fzero;

  auto stageA = [&](int c, int t, int l) {
    const int idx = l * 512 + tid;            // 0..2047
    const int row = idx >> 3, slot = idx & 7;
    gld_lds16(Ag + (size_t)row * F_DIM + t * BK + ((slot ^ (row & 7)) << 3),
              &L[c * TILE3 + idx * 8]);
  };
  auto stageB = [&](int c, int t, int l) {
    const int idx = l * 512 + tid;            // 0..1023
    const int row = idx >> 3, slot = idx & 7;
    gld_lds16(Bg + (size_t)row * F_DIM + t * BK + ((slot ^ (row & 7)) << 3),
              &L[c * TILE3 + ATILE + idx * 8]);
  };
  auto rdA = [&](int c, int row, int kg) {
    return *(const short8v*)&L[c * TILE3 + row * BK + ((kg ^ (row & 7)) << 3)];
  };
  auto rdB = [&](int c, int row, int kg) {
    return *(const short8v*)&L[c * TILE3 + ATILE + row * BK + ((kg ^ (row & 7)) << 3)];
  };

  // prologue: 2 tiles in flight (12 loads/thread); retire tile 0's oldest 6.
#pragma unroll
  for (int l = 0; l < 4; ++l) stageA(0, 0, l);
#pragma unroll
  for (int l = 0; l < 2; ++l) stageB(0, 0, l);
#pragma unroll
  for (int l = 0; l < 4; ++l) stageA(1, 1, l);
#pragma unroll
  for (int l = 0; l < 2; ++l) stageB(1, 1, l);
  asm volatile("s_waitcnt vmcnt(6)" ::: "memory");
  __builtin_amdgcn_s_barrier();

  for (int t = 0; t < NT; ++t) {
    const int cur = t % 3;
    const int nx2 = (t + 2) % 3;
    const bool pf = (t + 2) < NT;
    short8v a[8], b[4];

    // fragment reads: this wave's k-slice only (12 x ds_read_b128)
#pragma unroll
    for (int i = 0; i < 8; ++i) a[i] = rdA(cur, ar0 + i * 16, ks);
#pragma unroll
    for (int j = 0; j < 4; ++j) b[j] = rdB(cur, br0 + j * 16, ks);
    // prefetch tile t+2 (6 gld_lds)
    if (pf) {
      stageA(nx2, t + 2, 0); stageA(nx2, t + 2, 1);
      stageA(nx2, t + 2, 2); stageA(nx2, t + 2, 3);
      stageB(nx2, t + 2, 0); stageB(nx2, t + 2, 1);
    }
    __builtin_amdgcn_s_setprio(1);
#pragma unroll
    for (int i = 0; i < 8; ++i)
#pragma unroll
      for (int j = 0; j < 4; ++j)
        mfma_16x16x32_bf16(acc[i][j], a[i], b[j]);
    __builtin_amdgcn_s_setprio(0);
    // retire tile t+1's 6 loads (oldest); keep t+2's 6 in flight (T4).
    if (pf) asm volatile("s_waitcnt vmcnt(6)" ::: "memory");
    else    asm volatile("s_waitcnt vmcnt(0)" ::: "memory");
    __builtin_amdgcn_s_barrier();   // certifies buf[(t+1)%3]; also orders
                                    // next tile's staging vs this tile's reads
  }

  // ---- k-slice reduction: kz=1 dumps acc to LDS, kz=0 adds ----
  float* Lf = (float*)L;            // 36864 f32 available; need 4*8192
  if (kz == 1) {
#pragma unroll
    for (int i = 0; i < 8; ++i)
#pragma unroll
      for (int j = 0; j < 4; ++j)
#pragma unroll
        for (int r = 0; r < 4; ++r)
          Lf[wq * 8192 + (i * 16 + hk * 4 + r) * 64 + j * 16 + r16] = acc[i][j][r];
  }
  __syncthreads();

  if (kz == 0) {
#pragma unroll
    for (int i = 0; i < 8; ++i) {
      const int gm = m_off + m0 + wr * 128 + i * 16 + hk * 4;
#pragma unroll
      for (int j = 0; j < 4; ++j) {
        const int n = n0 + wc * 64 + j * 16 + r16;
        const float bn = b2[n];
#pragma unroll
        for (int r = 0; r < 4; ++r) {
          const float part = Lf[wq * 8192 + (i * 16 + hk * 4 + r) * 64 + j * 16 + r16];
          const size_t off = (size_t)(gm + r) * C_DIM + n;
          xio[off] = acc[i][j][r] + part + bn + xio[off];
        }
      }
    }
  }
}

// ---------------------------------------------------------------------------
// K5: LN2 in place on d_out (unchanged)
// ---------------------------------------------------------------------------
__global__ __launch_bounds__(256) void k_ln2(float* __restrict__ y,
                                             const float* __restrict__ g2,
                                             const float* __restrict__ be2) {
  const int row = blockIdx.x;
  const int tid = threadIdx.x;
  float* yr = y + (size_t)row * C_DIM;
  const float4 v = ((const float4*)yr)[tid];
  float s1 = v.x + v.y + v.z + v.w;
  float s2 = v.x * v.x + v.y * v.y + v.z * v.z + v.w * v.w;
#pragma unroll
  for (int off = 32; off; off >>= 1) {
    s1 += __shfl_xor(s1, off, 64);
    s2 += __shfl_xor(s2, off, 64);
  }
  __shared__ float red[8];
  const int lane = tid & 63, w = tid >> 6;
  if (lane == 0) { red[w] = s1; red[4 + w] = s2; }
  __syncthreads();
  s1 = red[0] + red[1] + red[2] + red[3];
  s2 = red[4] + red[5] + red[6] + red[7];
  const float mu  = s1 * (1.f / C_DIM);
  const float var = s2 * (1.f / C_DIM) - mu * mu;
  const float rs  = rsqrtf(var + 1e-5f);
  const float4 g = ((const float4*)g2)[tid];
  const float4 b = ((const float4*)be2)[tid];
  float4 o;
  o.x = (v.x - mu) * rs * g.x + b.x;
  o.y = (v.y - mu) * rs * g.y + b.y;
  o.z = (v.z - mu) * rs * g.z + b.z;
  o.w = (v.w - mu) * rs * g.w + b.w;
  ((float4*)yr)[tid] = o;
}

// ---------------------------------------------------------------------------
// Launch. ws layout: qf (512KB) | w2b (8MB) | R chunk (M-chunked, 256-row
// granular for BM=256). d_out doubles as x1 staging.
// ---------------------------------------------------------------------------
extern "C" void kernel_launch(void* const* d_in, const int* in_sizes, int n_in,
                              void* d_out, int out_size, void* d_ws, size_t ws_size,
                              hipStream_t stream) {
  const float* x   = (const float*)d_in[0];
  // d_in[1], d_in[2]: circuit params — RZ phases drop out of <Z>, unused.
  const float* w1  = (const float*)d_in[3];
  const float* b1  = (const float*)d_in[4];
  const float* w2  = (const float*)d_in[5];
  const float* b2  = (const float*)d_in[6];
  const float* g1  = (const float*)d_in[7];
  const float* be1 = (const float*)d_in[8];
  const float* g2  = (const float*)d_in[9];
  const float* be2 = (const float*)d_in[10];
  float* out = (float*)d_out;

  char* ws = (char*)d_ws;
  float* qf = (float*)ws;                                          // 512 KB
  unsigned short* w2b = (unsigned short*)(ws + 512 * 1024);        // 8 MB
  const size_t rbase = 512 * 1024 + (size_t)8 * 1024 * 1024;
  unsigned short* Rb = (unsigned short*)(ws + rbase);

  // chunk M so R fits in the remaining workspace (256-row granularity)
  int cm = M_TOK;
  const size_t avail = (ws_size > rbase) ? ws_size - rbase : 0;
  const size_t need = (size_t)M_TOK * F_DIM * 2;
  if (avail < need) {
    size_t rows = (avail / ((size_t)F_DIM * 2)) & ~(size_t)255;
    cm = (rows < 256) ? 256 : (int)rows;
  }

  k_attn_ln1<<<M_TOK, 256, 0, stream>>>(x, g1, be1, out, qf);
  k_w2cast<<<2048, 256, 0, stream>>>(w2, w2b);
  for (int c0 = 0; c0 < M_TOK; c0 += cm) {
    const int cur = (M_TOK - c0 < cm) ? (M_TOK - c0) : cm;
    k_ffn1<<<dim3(cur / 16, F_DIM / 64), 256, 0, stream>>>(
        qf + (size_t)c0 * NQ, w1, b1, Rb);
    k_gemm<<<dim3(cur / BM, C_DIM / BN), 512, 0, stream>>>(Rb, w2b, b2, out, c0);
  }
  k_ln2<<<M_TOK, 256, 0, stream>>>(out, g2, be2);
}

// Round 19
// 139.943 us; speedup vs baseline: 1.1477x; 1.1477x over previous
//
#include <hip/hip_runtime.h>

// Problem constants (B=4, T=2048, C=1024, H=16, dk=64, ffn=4096, nq=16)
#define M_TOK 8192
#define C_DIM 1024
#define F_DIM 4096
#define NQ    16

typedef __attribute__((ext_vector_type(8))) short short8v;
typedef __attribute__((ext_vector_type(4))) float f32x4;
typedef unsigned long long u64;

typedef __attribute__((address_space(1))) void as1_void;
typedef __attribute__((address_space(3))) void as3_void;

__device__ __forceinline__ void gld_lds16(const void* g, void* l) {
  __builtin_amdgcn_global_load_lds((as1_void*)g, (as3_void*)l, 16, 0, 0);
}

__device__ __forceinline__ unsigned short f2bf(float f) {
  unsigned int u = __float_as_uint(f);
  u += 0x7FFFu + ((u >> 16) & 1u);   // round-to-nearest-even
  return (unsigned short)(u >> 16);
}

// Verified mapping (rounds 2/6/7/11/14): D row (A-dim) = (lane>>4)*4 + reg, D col (B-dim) = lane&15.
__device__ __forceinline__ void mfma_16x16x32_bf16(f32x4& d, short8v a, short8v b) {
  asm("v_mfma_f32_16x16x32_bf16 %0, %1, %2, %0" : "+v"(d) : "v"(a), "v"(b));
}

// ---------------------------------------------------------------------------
// K1: per-head cumprod(cos) + residual + LN1.  (unchanged, verified)
// ---------------------------------------------------------------------------
__global__ __launch_bounds__(256) void k_attn_ln1(
    const float* __restrict__ x, const float* __restrict__ g1,
    const float* __restrict__ be1, float* __restrict__ x1,
    float* __restrict__ qf) {
  const int row  = blockIdx.x;
  const int tid  = threadIdx.x;
  const int lane = tid & 63;
  const int w    = tid >> 6;
  const float* xr = x + (size_t)row * C_DIM;

  float y[4];
  float s1 = 0.f, s2 = 0.f;
#pragma unroll
  for (int hi = 0; hi < 4; ++hi) {
    const int idx = (w * 4 + hi) * 64 + lane;
    const float v = xr[idx];
    float p = cosf(v);
#pragma unroll
    for (int off = 1; off < 64; off <<= 1) {
      const float up = __shfl_up(p, off, 64);
      if (lane >= off) p *= up;
    }
    const float yy = v + p;
    y[hi] = yy;
    s1 += yy;
    s2 += yy * yy;
  }
#pragma unroll
  for (int off = 32; off; off >>= 1) {
    s1 += __shfl_xor(s1, off, 64);
    s2 += __shfl_xor(s2, off, 64);
  }
  __shared__ float red[8];
  if (lane == 0) { red[w] = s1; red[4 + w] = s2; }
  __syncthreads();
  s1 = red[0] + red[1] + red[2] + red[3];
  s2 = red[4] + red[5] + red[6] + red[7];
  const float mu  = s1 * (1.f / C_DIM);
  const float var = s2 * (1.f / C_DIM) - mu * mu;   // biased, as torch
  const float rs  = rsqrtf(var + 1e-5f);

  float* x1r = x1 + (size_t)row * C_DIM;
#pragma unroll
  for (int hi = 0; hi < 4; ++hi) {
    const int idx = (w * 4 + hi) * 64 + lane;
    const float xv = (y[hi] - mu) * rs * g1[idx] + be1[idx];
    x1r[idx] = xv;
    if (w == 0 && hi == 0) {   // channels 0..63 live in wave 0 here
      const float c = cosf(xv);
      float run = 1.f, mine = 0.f;
#pragma unroll
      for (int k = 0; k < NQ; ++k) {
        const float ck = __shfl(c, k, 64);
        run *= ck;
        if (lane == k) mine = run;
      }
      if (lane < NQ) qf[(size_t)row * NQ + lane] = mine;
    }
  }
}

// ---------------------------------------------------------------------------
// K2: w2 fp32 -> bf16 (unchanged)
// ---------------------------------------------------------------------------
__global__ __launch_bounds__(256) void k_w2cast(const float* __restrict__ w2,
                                                unsigned short* __restrict__ w2b) {
  const int n4 = C_DIM * F_DIM / 4;
  for (int i = blockIdx.x * 256 + threadIdx.x; i < n4; i += gridDim.x * 256) {
    const float4 v = ((const float4*)w2)[i];
    u64 pk = (u64)f2bf(v.x) | ((u64)f2bf(v.y) << 16)
           | ((u64)f2bf(v.z) << 32) | ((u64)f2bf(v.w) << 48);
    ((u64*)w2b)[i] = pk;
  }
}

// ---------------------------------------------------------------------------
// K3 (v3): R = bf16(relu(q @ w1^T + b1)) — zero LDS / zero cross-thread.
// (unchanged from rounds 6-14 PASS)
// ---------------------------------------------------------------------------
__global__ __launch_bounds__(256) void k_ffn1(
    const float* __restrict__ qf, const float* __restrict__ w1,
    const float* __restrict__ b1, unsigned short* __restrict__ R) {
  const int tid  = threadIdx.x;
  const int lane = tid & 63;
  const int wv   = tid >> 6;
  const int r16  = lane & 15;
  const int hk   = lane >> 4;
  const int mb   = blockIdx.x * 16;              // 16 q-rows per block
  const int fb   = blockIdx.y * 64 + wv * 16;    // 16 f-cols per wave

  short8v a = short8v{0,0,0,0,0,0,0,0};
  short8v b = short8v{0,0,0,0,0,0,0,0};
  if (hk < 2) {   // k = hk*8 .. hk*8+7 < 16 carries real data; k>=16 stays 0
    const float* qa = qf + (size_t)(mb + r16) * NQ + hk * 8;
    const float4 a0 = *(const float4*)(qa);
    const float4 a1 = *(const float4*)(qa + 4);
    a[0] = (short)f2bf(a0.x); a[1] = (short)f2bf(a0.y);
    a[2] = (short)f2bf(a0.z); a[3] = (short)f2bf(a0.w);
    a[4] = (short)f2bf(a1.x); a[5] = (short)f2bf(a1.y);
    a[6] = (short)f2bf(a1.z); a[7] = (short)f2bf(a1.w);
    const float* wb = w1 + (size_t)(fb + r16) * NQ + hk * 8;
    const float4 b0 = *(const float4*)(wb);
    const float4 b1v = *(const float4*)(wb + 4);
    b[0] = (short)f2bf(b0.x); b[1] = (short)f2bf(b0.y);
    b[2] = (short)f2bf(b0.z); b[3] = (short)f2bf(b0.w);
    b[4] = (short)f2bf(b1v.x); b[5] = (short)f2bf(b1v.y);
    b[6] = (short)f2bf(b1v.z); b[7] = (short)f2bf(b1v.w);
  }

  f32x4 acc = {0.f, 0.f, 0.f, 0.f};
  mfma_16x16x32_bf16(acc, a, b);

  const int f = fb + r16;
  const float bn = b1[f];
#pragma unroll
  for (int r = 0; r < 4; ++r) {
    const int m = mb + hk * 4 + r;
    R[(size_t)m * F_DIM + f] = f2bf(fmaxf(acc[r] + bn, 0.f));
  }
}

// ---------------------------------------------------------------------------
// K4: R14-verified kernel (139.98us PASS), swizzle REVERTED (R18: T1 cost
// -18% / 3.4x HBM fetch — inputs are L3-fit, natural schedule already
// near-compulsory traffic; remap destroyed it).
// Wave grid 2Mx2Nx2K, triple-buffer 144KB, counted vmcnt(6), T2 swizzle.
// ---------------------------------------------------------------------------
#define BM 256
#define BN 128
#define BK 64
#define NT (F_DIM / BK)            // 64 K-tiles
#define ATILE (BM * BK)            // 16384 bf16 = 32KB
#define BTILE (BN * BK)            // 8192  bf16 = 16KB
#define TILE3 (ATILE + BTILE)      // 24576 bf16 = 48KB

__global__ __launch_bounds__(512) void k_gemm(
    const unsigned short* __restrict__ R, const unsigned short* __restrict__ W2,
    const float* __restrict__ b2, float* __restrict__ xio, int m_off) {
  __shared__ unsigned short L[3 * TILE3];   // 144KB
  const int tid = threadIdx.x;
  const int m0 = blockIdx.x * BM;           // chunk-local
  const int n0 = blockIdx.y * BN;
  const unsigned short* Ag = R + (size_t)m0 * F_DIM;
  const unsigned short* Bg = W2 + (size_t)n0 * F_DIM;

  const int lane = tid & 63;
  const int wv  = tid >> 6;     // 0..7
  const int kz  = wv >> 2;      // k-slice owner: 0 -> k 0..31, 1 -> k 32..63
  const int wq  = wv & 3;       // output-tile id (2M x 2N)
  const int wr  = wq >> 1;      // 0..1 (M dim, 128 rows each)
  const int wc  = wq & 1;       // 0..1 (N dim, 64 cols each)
  const int r16 = lane & 15;
  const int hk  = lane >> 4;
  const int ks  = hk + kz * 4;     // 8-elem k-group index within BK=64
  const int ar0 = wr * 128 + r16;  // A rows base for this lane
  const int br0 = wc * 64 + r16;   // B rows base

  f32x4 acc[8][4];
  const f32x4 fzero = {0.f, 0.f, 0.f, 0.f};
#pragma unroll
  for (int i = 0; i < 8; ++i)
#pragma unroll
    for (int j = 0; j < 4; ++j) acc[i][j] = fzero;

  auto stageA = [&](int c, int t, int l) {
    const int idx = l * 512 + tid;            // 0..2047
    const int row = idx >> 3, slot = idx & 7;
    gld_lds16(Ag + (size_t)row * F_DIM + t * BK + ((slot ^ (row & 7)) << 3),
              &L[c * TILE3 + idx * 8]);
  };
  auto stageB = [&](int c, int t, int l) {
    const int idx = l * 512 + tid;            // 0..1023
    const int row = idx >> 3, slot = idx & 7;
    gld_lds16(Bg + (size_t)row * F_DIM + t * BK + ((slot ^ (row & 7)) << 3),
              &L[c * TILE3 + ATILE + idx * 8]);
  };
  auto rdA = [&](int c, int row, int kg) {
    return *(const short8v*)&L[c * TILE3 + row * BK + ((kg ^ (row & 7)) << 3)];
  };
  auto rdB = [&](int c, int row, int kg) {
    return *(const short8v*)&L[c * TILE3 + ATILE + row * BK + ((kg ^ (row & 7)) << 3)];
  };

  // prologue: 2 tiles in flight (12 loads/thread); retire tile 0's oldest 6.
#pragma unroll
  for (int l = 0; l < 4; ++l) stageA(0, 0, l);
#pragma unroll
  for (int l = 0; l < 2; ++l) stageB(0, 0, l);
#pragma unroll
  for (int l = 0; l < 4; ++l) stageA(1, 1, l);
#pragma unroll
  for (int l = 0; l < 2; ++l) stageB(1, 1, l);
  asm volatile("s_waitcnt vmcnt(6)" ::: "memory");
  __builtin_amdgcn_s_barrier();

  for (int t = 0; t < NT; ++t) {
    const int cur = t % 3;
    const int nx2 = (t + 2) % 3;
    const bool pf = (t + 2) < NT;
    short8v a[8], b[4];

    // fragment reads: this wave's k-slice only (12 x ds_read_b128)
#pragma unroll
    for (int i = 0; i < 8; ++i) a[i] = rdA(cur, ar0 + i * 16, ks);
#pragma unroll
    for (int j = 0; j < 4; ++j) b[j] = rdB(cur, br0 + j * 16, ks);
    // prefetch tile t+2 (6 gld_lds)
    if (pf) {
      stageA(nx2, t + 2, 0); stageA(nx2, t + 2, 1);
      stageA(nx2, t + 2, 2); stageA(nx2, t + 2, 3);
      stageB(nx2, t + 2, 0); stageB(nx2, t + 2, 1);
    }
    __builtin_amdgcn_s_setprio(1);
#pragma unroll
    for (int i = 0; i < 8; ++i)
#pragma unroll
      for (int j = 0; j < 4; ++j)
        mfma_16x16x32_bf16(acc[i][j], a[i], b[j]);
    __builtin_amdgcn_s_setprio(0);
    // retire tile t+1's 6 loads (oldest); keep t+2's 6 in flight (T4).
    if (pf) asm volatile("s_waitcnt vmcnt(6)" ::: "memory");
    else    asm volatile("s_waitcnt vmcnt(0)" ::: "memory");
    __builtin_amdgcn_s_barrier();   // certifies buf[(t+1)%3]; also orders
                                    // next tile's staging vs this tile's reads
  }

  // ---- k-slice reduction: kz=1 dumps acc to LDS, kz=0 adds ----
  float* Lf = (float*)L;            // 36864 f32 available; need 4*8192
  if (kz == 1) {
#pragma unroll
    for (int i = 0; i < 8; ++i)
#pragma unroll
      for (int j = 0; j < 4; ++j)
#pragma unroll
        for (int r = 0; r < 4; ++r)
          Lf[wq * 8192 + (i * 16 + hk * 4 + r) * 64 + j * 16 + r16] = acc[i][j][r];
  }
  __syncthreads();

  if (kz == 0) {
#pragma unroll
    for (int i = 0; i < 8; ++i) {
      const int gm = m_off + m0 + wr * 128 + i * 16 + hk * 4;
#pragma unroll
      for (int j = 0; j < 4; ++j) {
        const int n = n0 + wc * 64 + j * 16 + r16;
        const float bn = b2[n];
#pragma unroll
        for (int r = 0; r < 4; ++r) {
          const float part = Lf[wq * 8192 + (i * 16 + hk * 4 + r) * 64 + j * 16 + r16];
          const size_t off = (size_t)(gm + r) * C_DIM + n;
          xio[off] = acc[i][j][r] + part + bn + xio[off];
        }
      }
    }
  }
}

// ---------------------------------------------------------------------------
// K5: LN2 in place on d_out (unchanged)
// ---------------------------------------------------------------------------
__global__ __launch_bounds__(256) void k_ln2(float* __restrict__ y,
                                             const float* __restrict__ g2,
                                             const float* __restrict__ be2) {
  const int row = blockIdx.x;
  const int tid = threadIdx.x;
  float* yr = y + (size_t)row * C_DIM;
  const float4 v = ((const float4*)yr)[tid];
  float s1 = v.x + v.y + v.z + v.w;
  float s2 = v.x * v.x + v.y * v.y + v.z * v.z + v.w * v.w;
#pragma unroll
  for (int off = 32; off; off >>= 1) {
    s1 += __shfl_xor(s1, off, 64);
    s2 += __shfl_xor(s2, off, 64);
  }
  __shared__ float red[8];
  const int lane = tid & 63, w = tid >> 6;
  if (lane == 0) { red[w] = s1; red[4 + w] = s2; }
  __syncthreads();
  s1 = red[0] + red[1] + red[2] + red[3];
  s2 = red[4] + red[5] + red[6] + red[7];
  const float mu  = s1 * (1.f / C_DIM);
  const float var = s2 * (1.f / C_DIM) - mu * mu;
  const float rs  = rsqrtf(var + 1e-5f);
  const float4 g = ((const float4*)g2)[tid];
  const float4 b = ((const float4*)be2)[tid];
  float4 o;
  o.x = (v.x - mu) * rs * g.x + b.x;
  o.y = (v.y - mu) * rs * g.y + b.y;
  o.z = (v.z - mu) * rs * g.z + b.z;
  o.w = (v.w - mu) * rs * g.w + b.w;
  ((float4*)yr)[tid] = o;
}

// ---------------------------------------------------------------------------
// Launch. ws layout: qf (512KB) | w2b (8MB) | R chunk (M-chunked, 256-row
// granular for BM=256). d_out doubles as x1 staging.
// ---------------------------------------------------------------------------
extern "C" void kernel_launch(void* const* d_in, const int* in_sizes, int n_in,
                              void* d_out, int out_size, void* d_ws, size_t ws_size,
                              hipStream_t stream) {
  const float* x   = (const float*)d_in[0];
  // d_in[1], d_in[2]: circuit params — RZ phases drop out of <Z>, unused.
  const float* w1  = (const float*)d_in[3];
  const float* b1  = (const float*)d_in[4];
  const float* w2  = (const float*)d_in[5];
  const float* b2  = (const float*)d_in[6];
  const float* g1  = (const float*)d_in[7];
  const float* be1 = (const float*)d_in[8];
  const float* g2  = (const float*)d_in[9];
  const float* be2 = (const float*)d_in[10];
  float* out = (float*)d_out;

  char* ws = (char*)d_ws;
  float* qf = (float*)ws;                                          // 512 KB
  unsigned short* w2b = (unsigned short*)(ws + 512 * 1024);        // 8 MB
  const size_t rbase = 512 * 1024 + (size_t)8 * 1024 * 1024;
  unsigned short* Rb = (unsigned short*)(ws + rbase);

  // chunk M so R fits in the remaining workspace (256-row granularity)
  int cm = M_TOK;
  const size_t avail = (ws_size > rbase) ? ws_size - rbase : 0;
  const size_t need = (size_t)M_TOK * F_DIM * 2;
  if (avail < need) {
    size_t rows = (avail / ((size_t)F_DIM * 2)) & ~(size_t)255;
    cm = (rows < 256) ? 256 : (int)rows;
  }

  k_attn_ln1<<<M_TOK, 256, 0, stream>>>(x, g1, be1, out, qf);
  k_w2cast<<<2048, 256, 0, stream>>>(w2, w2b);
  for (int c0 = 0; c0 < M_TOK; c0 += cm) {
    const int cur = (M_TOK - c0 < cm) ? (M_TOK - c0) : cm;
    k_ffn1<<<dim3(cur / 16, F_DIM / 64), 256, 0, stream>>>(
        qf + (size_t)c0 * NQ, w1, b1, Rb);
    k_gemm<<<dim3(cur / BM, C_DIM / BN), 512, 0, stream>>>(Rb, w2b, b2, out, c0);
  }
  k_ln2<<<M_TOK, 256, 0, stream>>>(out, g2, be2);
}